// Round 9
// baseline (924.224 us; speedup 1.0000x reference)
//
#include <hip/hip_runtime.h>
#include <hip/hip_bf16.h>
#include <cstdint>

// Sparse top-2 MoE (DBRX experts), MI355X gfx950.
// memset(cnt) -> fused{router | convert w1,v1,w2 -> bf16} -> scan -> assign
//   -> proj GEMM (H = silu(X w1^T)*(X v1^T)) -> down GEMM (outslot = gate*(H w2^T)) -> combine.
// GEMM (new this round): 256-row x 128-dual tiles, BK=64, 512 thr (8 waves, 4Mx2N,
// 64x64-dual per wave), double-buffered LDS (128 KB, 1 block/CU), counted-vmcnt pipeline:
//   per K-tile t:  compute(buf[p]) ; lgkmcnt(0)+barrier ;
//                  issue 8 gload_lds(t+2 -> buf[p]) ; vmcnt(8) ; barrier ; p^=1
// Proofs: t+2 writes issue only after the barrier following all reads of t (no W-after-R);
// vmcnt(8) leaves exactly the 8 newest loads (t+2) -> drains t+1 in every wave before the
// barrier (no other vmem instructions exist in the loop); load window = 1 full iteration.
// Staging/swizzle identical to the R6-proven scheme: 1 KiB chunks, linear LDS dest,
// source column-chunk pre-swizzled csw = (lane&7)^(row&7), reads decode with
// kb ^ ((row&7)<<4). Measured 0 bank conflicts across rounds 6-8.

#define T_TOK 4096
#define DHID  2048
#define NEXP  8
#define IDIM  4096
#define NSLOT (T_TOK * 2)

#define BM 256
#define BK 64

typedef __bf16 bf16x8 __attribute__((ext_vector_type(8)));
typedef __bf16 bf16x4 __attribute__((ext_vector_type(4)));
typedef float  f32x4  __attribute__((ext_vector_type(4)));

__device__ __forceinline__ void gload_lds16(const void* g, void* l) {
    __builtin_amdgcn_global_load_lds(
        (const __attribute__((address_space(1))) uint32_t*)g,
        (__attribute__((address_space(3))) uint32_t*)l, 16, 0, 0);
}

__device__ __forceinline__ void cvt8(const float* __restrict__ s, __bf16* __restrict__ d,
                                     size_t i) {
    const float4* sp = (const float4*)(s + i * 8);
    float4 a = sp[0], b = sp[1];
    bf16x8 o;
    o[0]=(__bf16)a.x; o[1]=(__bf16)a.y; o[2]=(__bf16)a.z; o[3]=(__bf16)a.w;
    o[4]=(__bf16)b.x; o[5]=(__bf16)b.y; o[6]=(__bf16)b.z; o[7]=(__bf16)b.w;
    *(bf16x8*)(d + i * 8) = o;
}

// ---------------- fused router + weight converts ----------------
__global__ __launch_bounds__(256) void router_cvt_kernel(
    const float* __restrict__ x, const float* __restrict__ wr,
    __bf16* __restrict__ xb, int* __restrict__ topi, float* __restrict__ topg,
    int* __restrict__ cnt,
    const float* __restrict__ w1, __bf16* __restrict__ wb1,
    const float* __restrict__ v1, __bf16* __restrict__ wv1,
    const float* __restrict__ w2, __bf16* __restrict__ wb2, size_t n8)
{
    if (blockIdx.x >= T_TOK / 4) {
        size_t cb = blockIdx.x - T_TOK / 4;
        size_t gid = cb * 256 + threadIdx.x;
        size_t stride = (size_t)(gridDim.x - T_TOK / 4) * 256;
        for (size_t i = gid; i < n8; i += stride) {
            cvt8(w1, wb1, i);
            cvt8(v1, wv1, i);
            if (w2) cvt8(w2, wb2, i);
        }
        return;
    }
    int wave = threadIdx.x >> 6, lane = threadIdx.x & 63;
    int t = blockIdx.x * 4 + wave;
    const float4* xr = (const float4*)(x + (size_t)t * DHID);
    bf16x4* xbo = (bf16x4*)(xb + (size_t)t * DHID);
    float acc[NEXP];
#pragma unroll
    for (int e = 0; e < NEXP; ++e) acc[e] = 0.f;
#pragma unroll
    for (int j = 0; j < DHID / 256; ++j) {
        int d4 = lane + j * 64;
        float4 v = xr[d4];
        bf16x4 bv;
        bv[0] = (__bf16)v.x; bv[1] = (__bf16)v.y;
        bv[2] = (__bf16)v.z; bv[3] = (__bf16)v.w;
        xbo[d4] = bv;
#pragma unroll
        for (int e = 0; e < NEXP; ++e) {
            float4 w = ((const float4*)(wr + e * DHID))[d4];
            acc[e] += v.x * w.x + v.y * w.y + v.z * w.z + v.w * w.w;
        }
    }
#pragma unroll
    for (int e = 0; e < NEXP; ++e) {
#pragma unroll
        for (int s = 32; s > 0; s >>= 1) acc[e] += __shfl_xor(acc[e], s);
    }
    if (lane == 0) {
        int e0 = 0; float l0 = acc[0];
#pragma unroll
        for (int e = 1; e < NEXP; ++e) if (acc[e] > l0) { l0 = acc[e]; e0 = e; }
        int e1 = -1; float l1 = -3.4e38f;
#pragma unroll
        for (int e = 0; e < NEXP; ++e) if (e != e0 && acc[e] > l1) { l1 = acc[e]; e1 = e; }
        float g0 = 1.f / (1.f + __expf(l1 - l0));
        topi[t * 2] = e0; topi[t * 2 + 1] = e1;
        topg[t * 2] = g0; topg[t * 2 + 1] = 1.f - g0;
        atomicAdd(&cnt[e0], 1); atomicAdd(&cnt[e1], 1);
    }
}

__global__ void scan_kernel(const int* __restrict__ cnt, int* __restrict__ basep,
                            int* __restrict__ fill)
{
    if (threadIdx.x == 0 && blockIdx.x == 0) {
        int s = 0;
#pragma unroll
        for (int e = 0; e < NEXP; ++e) { basep[e] = s; s += cnt[e]; fill[e] = 0; }
    }
}

__global__ __launch_bounds__(256) void assign_kernel(
    const int* __restrict__ topi, const float* __restrict__ topg,
    const int* __restrict__ basep, int* __restrict__ fill,
    int* __restrict__ tok_of_slot, float* __restrict__ gate_of_slot,
    int* __restrict__ slot_of)
{
    int t = blockIdx.x * 256 + threadIdx.x;
    if (t >= T_TOK) return;
#pragma unroll
    for (int k = 0; k < 2; ++k) {
        int e = topi[t * 2 + k];
        int slot = basep[e] + atomicAdd(&fill[e], 1);
        tok_of_slot[slot] = t;
        gate_of_slot[slot] = topg[t * 2 + k];
        slot_of[t * 2 + k] = slot;
    }
}

__global__ __launch_bounds__(256) void convert_kernel(
    const float* __restrict__ src, __bf16* __restrict__ dst, size_t n8)
{
    for (size_t i = (size_t)blockIdx.x * 256 + threadIdx.x; i < n8;
         i += (size_t)gridDim.x * 256) cvt8(src, dst, i);
}

// ---------------- pipelined dual GEMM ----------------
// PASS 1 (proj): acc1 = X w1^T, acc2 = X v1^T on a 256x128 (m,n) tile; n0 = bx*128;
//                epilogue H = silu(acc1)*acc2. A = xb gathered by toks.
// PASS 2 (down): dual-N: acc1 = H w2[n0..n0+128)^T, acc2 = H w2[n0+128..n0+256)^T;
//                n0 = bx*256; epilogue outslot = gate*acc. A = H contiguous by slot.
template <int PASS, int KDIM>
__global__ __launch_bounds__(512, 2) void moe_gemm(
    const __bf16* __restrict__ Abase,
    const __bf16* __restrict__ Wa, const __bf16* __restrict__ Wb,
    const int* __restrict__ tok_of_slot, const float* __restrict__ gate_of_slot,
    const int* __restrict__ cnt, const int* __restrict__ basep,
    __bf16* __restrict__ Out)
{
    int e  = blockIdx.z;
    int ne = cnt[e];
    int m0 = blockIdx.y * BM;
    if (m0 >= ne) return;
    int n0 = blockIdx.x * (PASS == 1 ? 128 : 256);
    int sbase = basep[e] + m0;

    __shared__ __bf16 As[2][BM * BK];        // 2 x 32 KiB
    __shared__ __bf16 B1s[2][128 * BK];      // 2 x 16 KiB
    __shared__ __bf16 B2s[2][128 * BK];      // 2 x 16 KiB
    __shared__ int   toks[BM];
    __shared__ float gates[BM];

    int tid = threadIdx.x, lane = tid & 63, wave = tid >> 6;
    char* AsB = (char*)&As[0][0];
    char* B1B = (char*)&B1s[0][0];
    char* B2B = (char*)&B2s[0][0];

    if (PASS == 1) {
        if (tid < BM) toks[tid] = (m0 + tid < ne) ? tok_of_slot[sbase + tid] : 0;
    } else {
        if (tid < BM) gates[tid] = gate_of_slot[(m0 + tid < ne) ? (sbase + tid) : sbase];
    }
    __syncthreads();

    // ---- A staging: 32 chunks of 1 KiB (wave*4+r), 4 gload/thread per tile.
    const __bf16* a_src[4];
    int a_coff[4];
#pragma unroll
    for (int r = 0; r < 4; ++r) {
        int chunk = wave * 4 + r;                 // 0..31
        int arow  = chunk * 8 + (lane >> 3);      // 0..255
        int csw   = (lane & 7) ^ (arow & 7);
        size_t rowbase;
        if (PASS == 1) {
            rowbase = (size_t)toks[arow] * KDIM;
        } else {
            int srow = (m0 + arow < ne) ? (sbase + arow) : sbase;
            rowbase = (size_t)srow * KDIM;
        }
        a_src[r]  = Abase + rowbase + csw * 8;
        a_coff[r] = chunk * 1024;
    }
    // ---- B staging: 16 chunks each (wave*2+r), 2+2 gload/thread per tile.
    const __bf16* b1_src[2];
    const __bf16* b2_src[2];
    int b_coff[2];
    {
        const __bf16* Wae;
        const __bf16* Wbe;
        if (PASS == 1) {
            Wae = Wa + (size_t)e * IDIM * DHID;
            Wbe = Wb + (size_t)e * IDIM * DHID;
        } else {
            Wae = Wa + (size_t)e * DHID * IDIM;
            Wbe = Wae + (size_t)128 * KDIM;
        }
#pragma unroll
        for (int r = 0; r < 2; ++r) {
            int chunk = wave * 2 + r;                 // 0..15
            int brow  = chunk * 8 + (lane >> 3);      // 0..127
            int csw   = (lane & 7) ^ (brow & 7);
            b1_src[r] = Wae + (size_t)(n0 + brow) * KDIM + csw * 8;
            b2_src[r] = Wbe + (size_t)(n0 + brow) * KDIM + csw * 8;
            b_coff[r] = chunk * 1024;
        }
    }

    int wm = wave >> 1;          // 0..3 -> rows wm*64
    int wn = wave & 1;           // 0..1 -> cols wn*64

    f32x4 acc1[4][4], acc2[4][4];
    f32x4 zf = {0.f, 0.f, 0.f, 0.f};
#pragma unroll
    for (int m = 0; m < 4; ++m)
#pragma unroll
        for (int n = 0; n < 4; ++n) { acc1[m][n] = zf; acc2[m][n] = zf; }

    const int NK = KDIM / BK;

#define ISSUE_TILE(T, BUF)                                                        \
    {                                                                             \
        int ko_ = (T) * BK;                                                       \
        _Pragma("unroll")                                                         \
        for (int r = 0; r < 4; ++r)                                               \
            gload_lds16(a_src[r] + ko_, AsB + (BUF) * 32768 + a_coff[r]);         \
        _Pragma("unroll")                                                         \
        for (int r = 0; r < 2; ++r)                                               \
            gload_lds16(b1_src[r] + ko_, B1B + (BUF) * 16384 + b_coff[r]);        \
        _Pragma("unroll")                                                         \
        for (int r = 0; r < 2; ++r)                                               \
            gload_lds16(b2_src[r] + ko_, B2B + (BUF) * 16384 + b_coff[r]);        \
    }

    // ---- prologue: tiles 0 and 1 in flight; drain tile 0; barrier.
    ISSUE_TILE(0, 0)
    ISSUE_TILE(1, 1)
    asm volatile("s_waitcnt vmcnt(8)" ::: "memory");
    __builtin_amdgcn_s_barrier();
    asm volatile("" ::: "memory");

    int p = 0;
    for (int t = 0; t < NK; ++t) {
        // compute tile t from buf[p] (compiler schedules ds_read/lgkmcnt/MFMA)
#pragma unroll
        for (int ks = 0; ks < 2; ++ks) {
            int kb = ks * 64 + (lane >> 4) * 16;
            bf16x8 af[4], b1f[4], b2f[4];
#pragma unroll
            for (int m = 0; m < 4; ++m) {
                int row = wm * 64 + m * 16 + (lane & 15);
                af[m] = *(const bf16x8*)(AsB + p * 32768 + row * 128 + (kb ^ ((row & 7) << 4)));
            }
#pragma unroll
            for (int n = 0; n < 4; ++n) {
                int row = wn * 64 + n * 16 + (lane & 15);
                int off = row * 128 + (kb ^ ((row & 7) << 4));
                b1f[n] = *(const bf16x8*)(B1B + p * 16384 + off);
                b2f[n] = *(const bf16x8*)(B2B + p * 16384 + off);
            }
#pragma unroll
            for (int m = 0; m < 4; ++m)
#pragma unroll
                for (int n = 0; n < 4; ++n) {
                    acc1[m][n] = __builtin_amdgcn_mfma_f32_16x16x32_bf16(af[m], b1f[n], acc1[m][n], 0, 0, 0);
                    acc2[m][n] = __builtin_amdgcn_mfma_f32_16x16x32_bf16(af[m], b2f[n], acc2[m][n], 0, 0, 0);
                }
        }
        // all waves done reading buf[p]
        asm volatile("s_waitcnt lgkmcnt(0)" ::: "memory");
        __builtin_amdgcn_s_barrier();
        asm volatile("" ::: "memory");
        // refill buf[p] with tile t+2; drain tile t+1; publish via barrier
        if (t + 2 < NK) {
            ISSUE_TILE(t + 2, p)
            asm volatile("s_waitcnt vmcnt(8)" ::: "memory");
        } else if (t + 1 < NK) {
            asm volatile("s_waitcnt vmcnt(0)" ::: "memory");
        }
        __builtin_amdgcn_s_barrier();
        asm volatile("" ::: "memory");
        p ^= 1;
    }
#undef ISSUE_TILE

    // ---- epilogue
#pragma unroll
    for (int m = 0; m < 4; ++m) {
        int rbase = wm * 64 + m * 16 + ((lane >> 4) * 4);
#pragma unroll
        for (int n = 0; n < 4; ++n) {
            int col = wn * 64 + n * 16 + (lane & 15);
#pragma unroll
            for (int r = 0; r < 4; ++r) {
                int lrow = rbase + r;
                if (m0 + lrow < ne) {
                    if (PASS == 1) {
                        float a = acc1[m][n][r];
                        float b = acc2[m][n][r];
                        float h = (a / (1.f + __expf(-a))) * b;
                        Out[(size_t)(sbase + lrow) * IDIM + n0 + col] = (__bf16)h;
                    } else {
                        float g = gates[lrow];
                        size_t obase = (size_t)(sbase + lrow) * DHID + n0;
                        Out[obase + col]       = (__bf16)(acc1[m][n][r] * g);
                        Out[obase + 128 + col] = (__bf16)(acc2[m][n][r] * g);
                    }
                }
            }
        }
    }
}

// ---------------- combine ----------------
__global__ __launch_bounds__(256) void combine_kernel(
    const __bf16* __restrict__ outslot, const int* __restrict__ slot_of,
    float* __restrict__ out)
{
    int idx = blockIdx.x * 256 + threadIdx.x;
    int t = idx >> 8;
    int c = (idx & 255) * 8;
    int s0 = slot_of[t * 2], s1 = slot_of[t * 2 + 1];
    bf16x8 a = *(const bf16x8*)(outslot + (size_t)s0 * DHID + c);
    bf16x8 b = *(const bf16x8*)(outslot + (size_t)s1 * DHID + c);
    float4 o0, o1;
    o0.x = (float)a[0] + (float)b[0];
    o0.y = (float)a[1] + (float)b[1];
    o0.z = (float)a[2] + (float)b[2];
    o0.w = (float)a[3] + (float)b[3];
    o1.x = (float)a[4] + (float)b[4];
    o1.y = (float)a[5] + (float)b[5];
    o1.z = (float)a[6] + (float)b[6];
    o1.w = (float)a[7] + (float)b[7];
    *(float4*)(out + (size_t)t * DHID + c)     = o0;
    *(float4*)(out + (size_t)t * DHID + c + 4) = o1;
}

extern "C" void kernel_launch(void* const* d_in, const int* in_sizes, int n_in,
                              void* d_out, int out_size, void* d_ws, size_t ws_size,
                              hipStream_t stream)
{
    (void)in_sizes; (void)n_in; (void)out_size;
    const float* x  = (const float*)d_in[0];
    const float* wr = (const float*)d_in[1];
    const float* w1 = (const float*)d_in[2];
    const float* v1 = (const float*)d_in[3];
    const float* w2 = (const float*)d_in[4];
    float* out = (float*)d_out;

    char* ws = (char*)d_ws;
    size_t off = 0;
    auto alloc = [&](size_t bytes) -> void* {
        void* p = ws + off;
        off += bytes;
        off = (off + 255) & ~(size_t)255;
        return p;
    };
    __bf16* xb      = (__bf16*)alloc((size_t)T_TOK * DHID * 2);
    __bf16* H       = (__bf16*)alloc((size_t)NSLOT * IDIM * 2);
    __bf16* outslot = (__bf16*)alloc((size_t)NSLOT * DHID * 2);
    int*    topi    = (int*)  alloc((size_t)T_TOK * 2 * 4);
    float*  topg    = (float*)alloc((size_t)T_TOK * 2 * 4);
    int*    tok_of_slot  = (int*)  alloc((size_t)NSLOT * 4);
    float*  gate_of_slot = (float*)alloc((size_t)NSLOT * 4);
    int*    slot_of = (int*)  alloc((size_t)NSLOT * 4);
    int*    cnt     = (int*)  alloc(NEXP * 4);
    int*    basep   = (int*)  alloc(NEXP * 4);
    int*    fill    = (int*)  alloc(NEXP * 4);

    const size_t EW   = (size_t)IDIM * DHID;
    const size_t WALL = (size_t)NEXP * EW;         // 67.1M elems / tensor
    __bf16* wb1 = (__bf16*)alloc(WALL * 2);
    __bf16* wv1 = (__bf16*)alloc(WALL * 2);
    bool roomy = (ws_size >= off + WALL * 2 + (16u << 20));
    __bf16* wb2 = roomy ? (__bf16*)alloc(WALL * 2) : wb1;

    hipMemsetAsync(cnt, 0, NEXP * 4, stream);
    // fused: router (blocks 0..1023) + weight converts (blocks 1024..5119)
    router_cvt_kernel<<<T_TOK / 4 + 4096, 256, 0, stream>>>(
        x, wr, xb, topi, topg, cnt,
        w1, wb1, v1, wv1, roomy ? w2 : nullptr, wb2, WALL / 8);
    scan_kernel<<<1, 64, 0, stream>>>(cnt, basep, fill);
    assign_kernel<<<T_TOK / 256, 256, 0, stream>>>(topi, topg, basep, fill,
                                                   tok_of_slot, gate_of_slot, slot_of);
    moe_gemm<1, DHID><<<dim3(IDIM / 128, NSLOT / BM, NEXP), 512, 0, stream>>>(
        xb, wb1, wv1, tok_of_slot, gate_of_slot, cnt, basep, H);
    if (!roomy) convert_kernel<<<2048, 256, 0, stream>>>(w2, wb2, WALL / 8);
    moe_gemm<2, IDIM><<<dim3(DHID / 256, NSLOT / BM, NEXP), 512, 0, stream>>>(
        H, wb2, nullptr, tok_of_slot, gate_of_slot, cnt, basep, outslot);
    combine_kernel<<<(T_TOK * DHID / 8) / 256, 256, 0, stream>>>(outslot, slot_of, out);
}

// Round 10
// 879.657 us; speedup vs baseline: 1.0507x; 1.0507x over previous
//
#include <hip/hip_runtime.h>
#include <hip/hip_bf16.h>
#include <cstdint>

// Sparse top-2 MoE (DBRX experts), MI355X gfx950.
// Launch graph (R8-proven):
//   memset(cnt) -> fused{router | convert w1,v1 -> bf16} -> scan -> assign
//     -> fused{proj GEMM (H = silu(X w1^T)*(X v1^T)) | convert w2 -> bf16}
//     -> down GEMM (outslot = gate*(H w2^T)) -> combine.
// GEMM skeleton unchanged from R6/R8 (3 blocks/CU TLP regime, 48.5 KB LDS, 2 syncthreads
// per K-tile, all-bf16 global_load_lds staging, verified swizzle pair, 0 bank conflicts).
// R10 change: inner MFMA switched 16x16x32 -> 32x32x16 (4060 vs 3378 FLOP/cy, half the
// MFMA instruction count). Fragments: A/B row=lane&31, k=(lane>>5)*8+j;
// C/D col=lane&31, row=(reg&3)+8*(reg>>2)+4*(lane>>5) [m74/m101 HW-verified].

#define T_TOK 4096
#define DHID  2048
#define NEXP  8
#define IDIM  4096
#define NSLOT (T_TOK * 2)

#define BM 128
#define BK 64

typedef __bf16 bf16x8 __attribute__((ext_vector_type(8)));
typedef __bf16 bf16x4 __attribute__((ext_vector_type(4)));
typedef float  f32x16 __attribute__((ext_vector_type(16)));

__device__ __forceinline__ void gload_lds16(const void* g, void* l) {
    __builtin_amdgcn_global_load_lds(
        (const __attribute__((address_space(1))) uint32_t*)g,
        (__attribute__((address_space(3))) uint32_t*)l, 16, 0, 0);
}

__device__ __forceinline__ void cvt8(const float* __restrict__ s, __bf16* __restrict__ d,
                                     size_t i) {
    const float4* sp = (const float4*)(s + i * 8);
    float4 a = sp[0], b = sp[1];
    bf16x8 o;
    o[0]=(__bf16)a.x; o[1]=(__bf16)a.y; o[2]=(__bf16)a.z; o[3]=(__bf16)a.w;
    o[4]=(__bf16)b.x; o[5]=(__bf16)b.y; o[6]=(__bf16)b.z; o[7]=(__bf16)b.w;
    *(bf16x8*)(d + i * 8) = o;
}

// ---------------- fused router + w1/v1 convert ----------------
__global__ __launch_bounds__(256) void router_cvt_kernel(
    const float* __restrict__ x, const float* __restrict__ wr,
    __bf16* __restrict__ xb, int* __restrict__ topi, float* __restrict__ topg,
    int* __restrict__ cnt,
    const float* __restrict__ w1, __bf16* __restrict__ wb1,
    const float* __restrict__ v1, __bf16* __restrict__ wv1, size_t n8)
{
    if (blockIdx.x >= T_TOK / 4) {
        size_t cb = blockIdx.x - T_TOK / 4;
        size_t gid = cb * 256 + threadIdx.x;
        size_t stride = (size_t)(gridDim.x - T_TOK / 4) * 256;
        for (size_t i = gid; i < n8; i += stride) {
            cvt8(w1, wb1, i);
            cvt8(v1, wv1, i);
        }
        return;
    }
    int wave = threadIdx.x >> 6, lane = threadIdx.x & 63;
    int t = blockIdx.x * 4 + wave;
    const float4* xr = (const float4*)(x + (size_t)t * DHID);
    bf16x4* xbo = (bf16x4*)(xb + (size_t)t * DHID);
    float acc[NEXP];
#pragma unroll
    for (int e = 0; e < NEXP; ++e) acc[e] = 0.f;
#pragma unroll
    for (int j = 0; j < DHID / 256; ++j) {
        int d4 = lane + j * 64;
        float4 v = xr[d4];
        bf16x4 bv;
        bv[0] = (__bf16)v.x; bv[1] = (__bf16)v.y;
        bv[2] = (__bf16)v.z; bv[3] = (__bf16)v.w;
        xbo[d4] = bv;
#pragma unroll
        for (int e = 0; e < NEXP; ++e) {
            float4 w = ((const float4*)(wr + e * DHID))[d4];
            acc[e] += v.x * w.x + v.y * w.y + v.z * w.z + v.w * w.w;
        }
    }
#pragma unroll
    for (int e = 0; e < NEXP; ++e) {
#pragma unroll
        for (int s = 32; s > 0; s >>= 1) acc[e] += __shfl_xor(acc[e], s);
    }
    if (lane == 0) {
        int e0 = 0; float l0 = acc[0];
#pragma unroll
        for (int e = 1; e < NEXP; ++e) if (acc[e] > l0) { l0 = acc[e]; e0 = e; }
        int e1 = -1; float l1 = -3.4e38f;
#pragma unroll
        for (int e = 0; e < NEXP; ++e) if (e != e0 && acc[e] > l1) { l1 = acc[e]; e1 = e; }
        float g0 = 1.f / (1.f + __expf(l1 - l0));
        topi[t * 2] = e0; topi[t * 2 + 1] = e1;
        topg[t * 2] = g0; topg[t * 2 + 1] = 1.f - g0;
        atomicAdd(&cnt[e0], 1); atomicAdd(&cnt[e1], 1);
    }
}

__global__ void scan_kernel(const int* __restrict__ cnt, int* __restrict__ basep,
                            int* __restrict__ fill)
{
    if (threadIdx.x == 0 && blockIdx.x == 0) {
        int s = 0;
#pragma unroll
        for (int e = 0; e < NEXP; ++e) { basep[e] = s; s += cnt[e]; fill[e] = 0; }
    }
}

__global__ __launch_bounds__(256) void assign_kernel(
    const int* __restrict__ topi, const float* __restrict__ topg,
    const int* __restrict__ basep, int* __restrict__ fill,
    int* __restrict__ tok_of_slot, float* __restrict__ gate_of_slot,
    int* __restrict__ slot_of)
{
    int t = blockIdx.x * 256 + threadIdx.x;
    if (t >= T_TOK) return;
#pragma unroll
    for (int k = 0; k < 2; ++k) {
        int e = topi[t * 2 + k];
        int slot = basep[e] + atomicAdd(&fill[e], 1);
        tok_of_slot[slot] = t;
        gate_of_slot[slot] = topg[t * 2 + k];
        slot_of[t * 2 + k] = slot;
    }
}

// ---------------- standalone convert (fallback path only) ----------------
__global__ __launch_bounds__(256) void convert_kernel(
    const float* __restrict__ src, __bf16* __restrict__ dst, size_t n8)
{
    for (size_t i = (size_t)blockIdx.x * 256 + threadIdx.x; i < n8;
         i += (size_t)gridDim.x * 256) cvt8(src, dst, i);
}

// ---------------- dual GEMM (R6/R8 skeleton, 32x32x16 MFMA) ----------------
// PASS 1 (proj): acc1 = X w1^T, acc2 = X v1^T on the same 128x128 tile;
//                epilogue H = silu(acc1)*acc2. A=xb gather; n0 = bx*128.
//                blockIdx.z == NEXP: grid-stride convert of w2 (exits before barriers).
// PASS 2 (down): dual-N: acc = H w2[n0..n0+256)^T; epilogue outslot = gate*acc.
template <int PASS, int KDIM>
__global__ __launch_bounds__(256, 2) void moe_gemm(
    const __bf16* __restrict__ Abase,
    const __bf16* __restrict__ Wa, const __bf16* __restrict__ Wb,
    const int* __restrict__ tok_of_slot, const float* __restrict__ gate_of_slot,
    const int* __restrict__ cnt, const int* __restrict__ basep,
    __bf16* __restrict__ Out,
    const float* __restrict__ cvt_src, __bf16* __restrict__ cvt_dst, size_t cvt_n8)
{
    int e = blockIdx.z;
    if (e >= NEXP) {
        size_t gid = ((size_t)blockIdx.y * gridDim.x + blockIdx.x) * 256 + threadIdx.x;
        size_t stride = (size_t)gridDim.x * gridDim.y * 256;
        for (size_t i = gid; i < cvt_n8; i += stride) cvt8(cvt_src, cvt_dst, i);
        return;
    }
    int ne = cnt[e];
    int m0 = blockIdx.y * BM;
    if (m0 >= ne) return;
    int n0 = blockIdx.x * (PASS == 1 ? 128 : 256);
    int sbase = basep[e] + m0;

    __shared__ __bf16 As[BM * BK];    // 16 KiB
    __shared__ __bf16 B1s[BM * BK];   // 16 KiB
    __shared__ __bf16 B2s[BM * BK];   // 16 KiB
    __shared__ int   toks[BM];
    __shared__ float gates[BM];

    int tid = threadIdx.x, lane = tid & 63, wave = tid >> 6;
    char* AsB = (char*)&As[0];
    char* B1B = (char*)&B1s[0];
    char* B2B = (char*)&B2s[0];

    if (PASS == 1) {
        if (tid < BM) toks[tid] = (m0 + tid < ne) ? tok_of_slot[sbase + tid] : 0;
    } else {
        if (tid < BM) gates[tid] = gate_of_slot[(m0 + tid < ne) ? (sbase + tid) : sbase];
    }
    __syncthreads();

    // A staging: 16 chunks of 1 KiB (wave-uniform dest), 4 gload_lds(16B)/thread.
    const __bf16* a_src[4];
    int coff[4];
#pragma unroll
    for (int r = 0; r < 4; ++r) {
        int chunk = wave * 4 + r;
        int arow  = chunk * 8 + (lane >> 3);
        int csw   = (lane & 7) ^ (arow & 7);
        size_t rowbase;
        if (PASS == 1) {
            rowbase = (size_t)toks[arow] * KDIM;
        } else {
            int srow = (m0 + arow < ne) ? (sbase + arow) : sbase;
            rowbase = (size_t)srow * KDIM;
        }
        a_src[r] = Abase + rowbase + csw * 8;
        coff[r]  = chunk * 1024;
    }

    // B staging: bf16 weights via gload_lds, same swizzle scheme.
    const __bf16* b1_src[4];
    const __bf16* b2_src[4];
    {
        const __bf16* Wae;
        const __bf16* Wbe;
        if (PASS == 1) {
            Wae = Wa + (size_t)e * IDIM * DHID;
            Wbe = Wb + (size_t)e * IDIM * DHID;
        } else {
            Wae = Wa + (size_t)e * DHID * IDIM;
            Wbe = Wae + (size_t)128 * KDIM;
        }
#pragma unroll
        for (int r = 0; r < 4; ++r) {
            int chunk = wave * 4 + r;
            int brow  = chunk * 8 + (lane >> 3);
            int csw   = (lane & 7) ^ (brow & 7);
            b1_src[r] = Wae + (size_t)(n0 + brow) * KDIM + csw * 8;
            b2_src[r] = Wbe + (size_t)(n0 + brow) * KDIM + csw * 8;
        }
    }

    int wr0 = (wave >> 1) * 64, wc0 = (wave & 1) * 64;

    f32x16 acc1[2][2], acc2[2][2];
#pragma unroll
    for (int m = 0; m < 2; ++m)
#pragma unroll
        for (int n = 0; n < 2; ++n) {
#pragma unroll
            for (int r = 0; r < 16; ++r) { acc1[m][n][r] = 0.f; acc2[m][n][r] = 0.f; }
        }

    const int NK = KDIM / BK;
    for (int t = 0; t < NK; ++t) {
        int ko = t * BK;
#pragma unroll
        for (int r = 0; r < 4; ++r) gload_lds16(a_src[r] + ko, AsB + coff[r]);
#pragma unroll
        for (int r = 0; r < 4; ++r) gload_lds16(b1_src[r] + ko, B1B + coff[r]);
#pragma unroll
        for (int r = 0; r < 4; ++r) gload_lds16(b2_src[r] + ko, B2B + coff[r]);
        __syncthreads();   // drains gload_lds (implicit vmcnt 0) + publishes LDS
        // compute tile t: 4 k-slices of 16, 2x2 32x32 frags, dual-B
#pragma unroll
        for (int ks = 0; ks < 4; ++ks) {
            int kb = ks * 32 + (lane >> 5) * 16;   // byte offset of this lane's 8 k-elems
            bf16x8 af[2], b1f[2], b2f[2];
#pragma unroll
            for (int m = 0; m < 2; ++m) {
                int row = wr0 + m * 32 + (lane & 31);
                af[m] = *(const bf16x8*)(AsB + row * 128 + (kb ^ ((row & 7) << 4)));
            }
#pragma unroll
            for (int n = 0; n < 2; ++n) {
                int row = wc0 + n * 32 + (lane & 31);
                int off = row * 128 + (kb ^ ((row & 7) << 4));
                b1f[n] = *(const bf16x8*)(B1B + off);
                b2f[n] = *(const bf16x8*)(B2B + off);
            }
#pragma unroll
            for (int m = 0; m < 2; ++m)
#pragma unroll
                for (int n = 0; n < 2; ++n) {
                    acc1[m][n] = __builtin_amdgcn_mfma_f32_32x32x16_bf16(af[m], b1f[n], acc1[m][n], 0, 0, 0);
                    acc2[m][n] = __builtin_amdgcn_mfma_f32_32x32x16_bf16(af[m], b2f[n], acc2[m][n], 0, 0, 0);
                }
        }
        __syncthreads();   // reads done before next tile's staging writes
    }

    // ---- epilogue: C/D col=lane&31, row=(reg&3)+8*(reg>>2)+4*(lane>>5)
#pragma unroll
    for (int m = 0; m < 2; ++m) {
#pragma unroll
        for (int n = 0; n < 2; ++n) {
            int col = wc0 + n * 32 + (lane & 31);
#pragma unroll
            for (int r = 0; r < 16; ++r) {
                int lrow = wr0 + m * 32 + (r & 3) + 8 * (r >> 2) + 4 * (lane >> 5);
                if (m0 + lrow < ne) {
                    if (PASS == 1) {
                        float a = acc1[m][n][r];
                        float b = acc2[m][n][r];
                        float h = (a / (1.f + __expf(-a))) * b;
                        Out[(size_t)(sbase + lrow) * IDIM + n0 + col] = (__bf16)h;
                    } else {
                        float g = gates[lrow];
                        size_t obase = (size_t)(sbase + lrow) * DHID + n0;
                        Out[obase + col]       = (__bf16)(acc1[m][n][r] * g);
                        Out[obase + 128 + col] = (__bf16)(acc2[m][n][r] * g);
                    }
                }
            }
        }
    }
}

// ---------------- combine ----------------
__global__ __launch_bounds__(256) void combine_kernel(
    const __bf16* __restrict__ outslot, const int* __restrict__ slot_of,
    float* __restrict__ out)
{
    int idx = blockIdx.x * 256 + threadIdx.x;
    int t = idx >> 8;
    int c = (idx & 255) * 8;
    int s0 = slot_of[t * 2], s1 = slot_of[t * 2 + 1];
    bf16x8 a = *(const bf16x8*)(outslot + (size_t)s0 * DHID + c);
    bf16x8 b = *(const bf16x8*)(outslot + (size_t)s1 * DHID + c);
    float4 o0, o1;
    o0.x = (float)a[0] + (float)b[0];
    o0.y = (float)a[1] + (float)b[1];
    o0.z = (float)a[2] + (float)b[2];
    o0.w = (float)a[3] + (float)b[3];
    o1.x = (float)a[4] + (float)b[4];
    o1.y = (float)a[5] + (float)b[5];
    o1.z = (float)a[6] + (float)b[6];
    o1.w = (float)a[7] + (float)b[7];
    *(float4*)(out + (size_t)t * DHID + c)     = o0;
    *(float4*)(out + (size_t)t * DHID + c + 4) = o1;
}

extern "C" void kernel_launch(void* const* d_in, const int* in_sizes, int n_in,
                              void* d_out, int out_size, void* d_ws, size_t ws_size,
                              hipStream_t stream)
{
    (void)in_sizes; (void)n_in; (void)out_size;
    const float* x  = (const float*)d_in[0];
    const float* wr = (const float*)d_in[1];
    const float* w1 = (const float*)d_in[2];
    const float* v1 = (const float*)d_in[3];
    const float* w2 = (const float*)d_in[4];
    float* out = (float*)d_out;

    char* ws = (char*)d_ws;
    size_t off = 0;
    auto alloc = [&](size_t bytes) -> void* {
        void* p = ws + off;
        off += bytes;
        off = (off + 255) & ~(size_t)255;
        return p;
    };
    __bf16* xb      = (__bf16*)alloc((size_t)T_TOK * DHID * 2);
    __bf16* H       = (__bf16*)alloc((size_t)NSLOT * IDIM * 2);
    __bf16* outslot = (__bf16*)alloc((size_t)NSLOT * DHID * 2);
    int*    topi    = (int*)  alloc((size_t)T_TOK * 2 * 4);
    float*  topg    = (float*)alloc((size_t)T_TOK * 2 * 4);
    int*    tok_of_slot  = (int*)  alloc((size_t)NSLOT * 4);
    float*  gate_of_slot = (float*)alloc((size_t)NSLOT * 4);
    int*    slot_of = (int*)  alloc((size_t)NSLOT * 4);
    int*    cnt     = (int*)  alloc(NEXP * 4);
    int*    basep   = (int*)  alloc(NEXP * 4);
    int*    fill    = (int*)  alloc(NEXP * 4);

    const size_t EW   = (size_t)IDIM * DHID;       // 8.39M elems / expert / tensor
    const size_t WALL = (size_t)NEXP * EW;         // 67.1M elems / tensor
    __bf16* wb1 = (__bf16*)alloc(WALL * 2);
    __bf16* wv1 = (__bf16*)alloc(WALL * 2);
    bool roomy = (ws_size >= off + WALL * 2 + (16u << 20));
    __bf16* wb2 = roomy ? (__bf16*)alloc(WALL * 2) : wb1;   // fallback: alias (serial path)

    hipMemsetAsync(cnt, 0, NEXP * 4, stream);
    // fused: router (blocks 0..1023) + w1/v1 convert (blocks 1024..5119)
    router_cvt_kernel<<<T_TOK / 4 + 4096, 256, 0, stream>>>(
        x, wr, xb, topi, topg, cnt, w1, wb1, v1, wv1, WALL / 8);
    scan_kernel<<<1, 64, 0, stream>>>(cnt, basep, fill);
    assign_kernel<<<T_TOK / 256, 256, 0, stream>>>(topi, topg, basep, fill,
                                                   tok_of_slot, gate_of_slot, slot_of);
    if (roomy) {
        // proj with fused w2 convert in the z==NEXP slice
        moe_gemm<1, DHID><<<dim3(IDIM / 128, NSLOT / BM, NEXP + 1), 256, 0, stream>>>(
            xb, wb1, wv1, tok_of_slot, gate_of_slot, cnt, basep, H, w2, wb2, WALL / 8);
    } else {
        moe_gemm<1, DHID><<<dim3(IDIM / 128, NSLOT / BM, NEXP), 256, 0, stream>>>(
            xb, wb1, wv1, tok_of_slot, gate_of_slot, cnt, basep, H, nullptr, nullptr, 0);
        convert_kernel<<<2048, 256, 0, stream>>>(w2, wb2, WALL / 8);
    }
    moe_gemm<2, IDIM><<<dim3(DHID / 256, NSLOT / BM, NEXP), 256, 0, stream>>>(
        H, wb2, nullptr, tok_of_slot, gate_of_slot, cnt, basep, outslot,
        nullptr, nullptr, 0);
    combine_kernel<<<(T_TOK * DHID / 8) / 256, 256, 0, stream>>>(outslot, slot_of, out);
}